// Round 3
// baseline (396.493 us; speedup 1.0000x reference)
//
#include <hip/hip_runtime.h>

#pragma clang fp contract(off)

#define NBOX 262144
#define NCLS 80
#define ROWS 85
#define CAP 1024
#define POOL 8192

// ---------------- init: zero counters (ws is poisoned 0xAA each call)
__global__ __launch_bounds__(128) void k_init(int* __restrict__ cls_count,
                                              int* __restrict__ pool_count,
                                              int* __restrict__ vcount) {
    int t = threadIdx.x;
    if (t < NCLS) cls_count[t] = 0;
    if (t == NCLS) *pool_count = 0;
    if (t == NCLS + 1) *vcount = 0;
}

// ---------------- stage1a: obj scan + block-aggregated compaction of valid indices
__global__ __launch_bounds__(256) void k_scan(const float* __restrict__ det,
                                              int* __restrict__ vcount,
                                              int* __restrict__ vidx) {
    __shared__ int ws[4];
    __shared__ int wbase;
    const int t = threadIdx.x;
    const int i = blockIdx.x * 256 + t;
    float obj = det[(long long)i * ROWS + 4];
    bool valid = (obj >= 0.8f);   // CONF_THRES
    unsigned long long m = __ballot(valid);
    const int wid = t >> 6, lane = t & 63;
    if (lane == 0) ws[wid] = __popcll(m);
    __syncthreads();
    if (t == 0) {
        int s = 0;
        #pragma unroll
        for (int w = 0; w < 4; w++) { int c = ws[w]; ws[w] = s; s += c; }
        wbase = atomicAdd(vcount, s);   // ONE global atomic per block
    }
    __syncthreads();
    if (valid) {
        int pos = wbase + ws[wid] + __popcll(m & ((1ull << lane) - 1ull));
        vidx[pos] = i;
    }
}

// ---------------- stage1b: one wave per valid box — coalesced row read + shuffle argmax
__global__ __launch_bounds__(256) void k_classify(const float* __restrict__ det,
                                                  const int* __restrict__ vcount,
                                                  const int* __restrict__ vidx,
                                                  float* __restrict__ cls_score,
                                                  int* __restrict__ cls_idx,
                                                  float* __restrict__ cls_conf,
                                                  float4* __restrict__ cls_box,
                                                  int* __restrict__ cls_count) {
    const int t = threadIdx.x;
    const int lane = t & 63;
    const int gw = (blockIdx.x * 256 + t) >> 6;   // global wave id, 0..4095
    const int total = *vcount;
    for (int v = gw; v < total; v += 4096) {
        const int i = vidx[v];
        const float* p = det + (long long)i * ROWS;
        // candidate 1: class = lane (cols 5..68), coalesced 64 consecutive floats
        float v1 = p[5 + lane];
        int i1 = lane;
        // lanes 0..15: classes 64..79 (cols 69..84); lanes 16..20: cols 0..4 (box+obj)
        float aux = 0.0f;
        if (lane < 21) aux = p[(lane < 16) ? (69 + lane) : (lane - 16)];
        if (lane < 16) {
            if (aux > v1) { v1 = aux; i1 = 64 + lane; }   // higher class: strict >
        }
        // wave argmax reduce: max value, lowest class index on ties (jnp.argmax)
        #pragma unroll
        for (int off = 32; off > 0; off >>= 1) {
            float ov = __shfl_xor(v1, off);
            int oi = __shfl_xor(i1, off);
            if (ov > v1 || (ov == v1 && oi < i1)) { v1 = ov; i1 = oi; }
        }
        float x = __shfl(aux, 16), y = __shfl(aux, 17);
        float w = __shfl(aux, 18), h = __shfl(aux, 19);
        float obj = __shfl(aux, 20);
        if (lane == 0) {
            float hw = w * 0.5f, hh = h * 0.5f;
            float score = obj * v1;
            int pos = atomicAdd(&cls_count[i1], 1);
            if (pos < CAP) {
                int o = i1 * CAP + pos;
                cls_score[o] = score;
                cls_idx[o] = i;
                cls_conf[o] = v1;
                cls_box[o] = make_float4(x - hw, y - hh, x + hw, y + hh);
            }
        }
    }
}

// ---------------- stage2+3: per-class sort (score desc, idx asc) + greedy NMS
__global__ __launch_bounds__(256) void k_nms(const float* __restrict__ cls_score,
                                             const int* __restrict__ cls_idx,
                                             const float* __restrict__ cls_conf,
                                             const float4* __restrict__ cls_box,
                                             const int* __restrict__ cls_count,
                                             unsigned long long* __restrict__ pool_key,
                                             float* __restrict__ pool_conf,
                                             int* __restrict__ pool_cls,
                                             int* __restrict__ pool_count) {
    __shared__ unsigned long long key[CAP];   // (~score_bits)<<32 | orig_idx
    __shared__ unsigned short slot[CAP];
    __shared__ float4 bx[CAP];
    __shared__ float cf[CAP];
    __shared__ unsigned words[CAP / 32];      // alive bitmask
    __shared__ int s_cur;
    const int c = blockIdx.x;
    const int t = threadIdx.x;
    const int n = min(cls_count[c], CAP);

    for (int p = t; p < CAP; p += 256) {
        if (p < n) {
            unsigned sb = __float_as_uint(cls_score[c * CAP + p]);  // score >= 0
            key[p] = ((unsigned long long)(~sb) << 32) | (unsigned)cls_idx[c * CAP + p];
        } else {
            key[p] = ~0ULL;
        }
        slot[p] = (unsigned short)p;
    }
    if (t < CAP / 32) {
        int lo = t << 5;
        words[t] = (n >= lo + 32) ? 0xFFFFFFFFu
                                  : (n > lo ? ((1u << (n - lo)) - 1u) : 0u);
    }
    __syncthreads();

    // bitonic sort ascending: score desc, ties orig-idx asc (stable-argsort match)
    for (int k = 2; k <= CAP; k <<= 1) {
        for (int j = k >> 1; j > 0; j >>= 1) {
            for (int i = t; i < CAP; i += 256) {
                int ixj = i ^ j;
                if (ixj > i) {
                    unsigned long long a = key[i], b = key[ixj];
                    if ((a > b) == ((i & k) == 0)) {
                        key[i] = b; key[ixj] = a;
                        unsigned short sv = slot[i]; slot[i] = slot[ixj]; slot[ixj] = sv;
                    }
                }
            }
            __syncthreads();
        }
    }

    // gather payload in sorted order
    for (int p = t; p < n; p += 256) {
        int sv = slot[p];
        bx[p] = cls_box[c * CAP + sv];
        cf[p] = cls_conf[c * CAP + sv];
    }

    // greedy NMS: bitmask find-first + parallel IoU pass per pick
    int cur = -1;
    const int nw = (n + 31) >> 5;
    while (true) {
        __syncthreads();   // publish payload / bitmask updates
        if (t == 0) {
            int nxt = -1;
            int start = cur + 1;
            if (start < n) {
                int w = start >> 5;
                unsigned m = words[w] & (0xFFFFFFFFu << (start & 31));
                while (true) {
                    if (m) { nxt = (w << 5) + __ffs(m) - 1; break; }
                    if (++w >= nw) break;
                    m = words[w];
                }
            }
            s_cur = nxt;
        }
        __syncthreads();
        cur = s_cur;
        if (cur < 0) break;

        float4 curb = bx[cur];
        float a1 = (curb.z - curb.x + 1.0f) * (curb.w - curb.y + 1.0f);
        for (int j = cur + 1 + t; j < n; j += 256) {
            if ((words[j >> 5] >> (j & 31)) & 1u) {
                float4 b = bx[j];
                float xx1 = fmaxf(curb.x, b.x);
                float yy1 = fmaxf(curb.y, b.y);
                float xx2 = fminf(curb.z, b.z);
                float yy2 = fminf(curb.w, b.w);
                float iw = xx2 - xx1 + 1.0f;
                float ih = yy2 - yy1 + 1.0f;
                float inter = fmaxf(iw, 0.0f) * fmaxf(ih, 0.0f);
                float a2 = (b.z - b.x + 1.0f) * (b.w - b.y + 1.0f);
                float iou = inter / (a1 + a2 - inter + 1e-16f);
                if (iou > 0.4f)   // NMS_THRES
                    atomicAnd(&words[j >> 5], ~(1u << (j & 31)));
            }
        }
        if (t == 0) {
            int pp = atomicAdd(pool_count, 1);
            if (pp < POOL) {
                unsigned long long lk = key[cur];
                // repack: (~score)<<31 | orig_idx(18b)<<13 | pool_idx(13b)
                pool_key[pp] = ((lk >> 32) << 31) | ((lk & 0xFFFFFFFFull) << 13) |
                               (unsigned long long)pp;
                pool_conf[pp] = cf[cur];
                pool_cls[pp] = c;
            }
        }
    }
}

// ---------------- stage4: global top-300 by score-key, then conf re-sort, output
__global__ __launch_bounds__(1024) void k_final(const unsigned long long* __restrict__ pool_key,
                                                const float* __restrict__ pool_conf,
                                                const int* __restrict__ pool_cls,
                                                const int* __restrict__ pool_count,
                                                float* __restrict__ out) {
    __shared__ unsigned long long skey[POOL];  // 64 KB
    const int t = threadIdx.x;
    const int K = min(*pool_count, POOL);
    for (int i = t; i < POOL; i += 1024) skey[i] = (i < K) ? pool_key[i] : ~0ULL;
    __syncthreads();

    int P = 512;
    while (P < K) P <<= 1;  // runtime-sized bitonic, P >= 512 > 300
    for (int k = 2; k <= P; k <<= 1) {
        for (int j = k >> 1; j > 0; j >>= 1) {
            for (int i = t; i < P; i += 1024) {
                int ixj = i ^ j;
                if (ixj > i) {
                    unsigned long long a = skey[i], b = skey[ixj];
                    if ((a > b) == ((i & k) == 0)) { skey[i] = b; skey[ixj] = a; }
                }
            }
            __syncthreads();
        }
    }

    // Final order: conf desc, ties slot desc (= reversed stable argsort)
    const int M = min(K, 300);
    unsigned long long k2 = ~0ULL;
    unsigned cb = 0;
    int mycls = 0;
    if (t < M) {
        int pidx = (int)(skey[t] & 0x1FFFull);
        float cfv = pool_conf[pidx];
        mycls = pool_cls[pidx];
        cb = __float_as_uint(cfv);
        k2 = ((unsigned long long)(~cb) << 32) | (unsigned)(~t);
    }
    __syncthreads();
    if (t < 512) skey[t] = k2;  // t in [M,512) pads with ~0ULL
    if (t < M) {
        skey[1024 + t] = cb;
        skey[2048 + t] = (unsigned long long)(unsigned)mycls;
    }
    __syncthreads();
    for (int k = 2; k <= 512; k <<= 1) {
        for (int j = k >> 1; j > 0; j >>= 1) {
            for (int i = t; i < 512; i += 1024) {
                int ixj = i ^ j;
                if (ixj > i) {
                    unsigned long long a = skey[i], b = skey[ixj];
                    if ((a > b) == ((i & k) == 0)) { skey[i] = b; skey[ixj] = a; }
                }
            }
            __syncthreads();
        }
    }

    if (t < 300) {
        float idv = 0.0f, pv = 0.0f;
        if (t < M) {
            unsigned long long kk = skey[t];
            int slotv = (int)(~(unsigned)(kk & 0xFFFFFFFFull));
            pv = __uint_as_float((unsigned)skey[1024 + slotv]);
            idv = (float)(int)skey[2048 + slotv];
        }
        out[t] = idv;        // ids (1,300)
        out[300 + t] = pv;   // probs (300,)
    }
}

extern "C" void kernel_launch(void* const* d_in, const int* in_sizes, int n_in,
                              void* d_out, int out_size, void* d_ws, size_t ws_size,
                              hipStream_t stream) {
    const float* det = (const float*)d_in[0];
    float* out = (float*)d_out;
    char* ws = (char*)d_ws;

    // workspace layout (~3.4 MB total)
    int* cls_count = (int*)(ws);                      // 80*4
    int* pool_count = (int*)(ws + 384);
    int* vcount = (int*)(ws + 448);
    float* cls_score = (float*)(ws + 512);            // 327680
    int* cls_idx = (int*)(ws + 328192);               // 327680
    float* cls_conf = (float*)(ws + 655872);          // 327680
    float4* cls_box = (float4*)(ws + 983552);         // 1310720 (16B aligned)
    unsigned long long* pool_key = (unsigned long long*)(ws + 2294272);  // 65536
    float* pool_conf = (float*)(ws + 2359808);        // 32768
    int* pool_cls = (int*)(ws + 2392576);             // 32768
    int* vidx = (int*)(ws + 2425344);                 // 1048576

    k_init<<<1, 128, 0, stream>>>(cls_count, pool_count, vcount);
    k_scan<<<NBOX / 256, 256, 0, stream>>>(det, vcount, vidx);
    k_classify<<<1024, 256, 0, stream>>>(det, vcount, vidx, cls_score, cls_idx,
                                         cls_conf, cls_box, cls_count);
    k_nms<<<NCLS, 256, 0, stream>>>(cls_score, cls_idx, cls_conf, cls_box, cls_count,
                                    pool_key, pool_conf, pool_cls, pool_count);
    k_final<<<1, 1024, 0, stream>>>(pool_key, pool_conf, pool_cls, pool_count, out);
}

// Round 4
// 283.559 us; speedup vs baseline: 1.3983x; 1.3983x over previous
//
#include <hip/hip_runtime.h>

#pragma clang fp contract(off)

#define NBOX 262144
#define NCLS 80
#define ROWS 85
#define CAP 1024
#define POOL 8192
#define VMAX 131072   // cap on compacted valid boxes (expected ~52.4K)

// ---------------- init: zero the two scalar counters
__global__ __launch_bounds__(64) void k_init(int* __restrict__ vcount,
                                             int* __restrict__ pool_count) {
    if (threadIdx.x == 0) { *vcount = 0; *pool_count = 0; }
}

// ---------------- stage1a: obj scan + block-aggregated compaction (1 atomic/block)
__global__ __launch_bounds__(256) void k_scan(const float* __restrict__ det,
                                              int* __restrict__ vcount,
                                              int* __restrict__ vidx) {
    __shared__ int wsum[4];
    __shared__ int wbase;
    const int t = threadIdx.x;
    const int i = blockIdx.x * 256 + t;
    float obj = det[(long long)i * ROWS + 4];
    bool valid = (obj >= 0.8f);   // CONF_THRES
    unsigned long long m = __ballot(valid);
    const int wid = t >> 6, lane = t & 63;
    if (lane == 0) wsum[wid] = (int)__popcll(m);
    __syncthreads();
    if (t == 0) {
        int s = 0;
        #pragma unroll
        for (int w = 0; w < 4; w++) { int c = wsum[w]; wsum[w] = s; s += c; }
        wbase = atomicAdd(vcount, s);   // single low-contention atomic per block
    }
    __syncthreads();
    if (valid) {
        int pos = wbase + wsum[wid] + (int)__popcll(m & ((1ull << lane) - 1ull));
        if (pos < VMAX) vidx[pos] = i;
    }
}

// ---------------- stage1b: one wave per valid box, dense v-order output, NO atomics
__global__ __launch_bounds__(256) void k_classify(const float* __restrict__ det,
                                                  const int* __restrict__ vcount,
                                                  const int* __restrict__ vidx,
                                                  int* __restrict__ cls_v,
                                                  float* __restrict__ score_v,
                                                  float* __restrict__ conf_v,
                                                  float4* __restrict__ box_v) {
    const int t = threadIdx.x, lane = t & 63;
    const int gw = (blockIdx.x * 256 + t) >> 6;
    const int stride = (gridDim.x * 256) >> 6;
    const int total = min(*vcount, VMAX);
    for (int v = gw; v < total; v += stride) {
        const int i = vidx[v];
        const float* p = det + (long long)i * ROWS;
        // classes 0..63 from lanes; 64..79 + box/obj from aux (verified in R3)
        float v1 = p[5 + lane];
        int i1 = lane;
        float aux = 0.0f;
        if (lane < 21) aux = p[(lane < 16) ? (69 + lane) : (lane - 16)];
        if (lane < 16 && aux > v1) { v1 = aux; i1 = 64 + lane; }
        #pragma unroll
        for (int off = 32; off > 0; off >>= 1) {
            float ov = __shfl_xor(v1, off);
            int oi = __shfl_xor(i1, off);
            if (ov > v1 || (ov == v1 && oi < i1)) { v1 = ov; i1 = oi; }
        }
        float x = __shfl(aux, 16), y = __shfl(aux, 17);
        float w = __shfl(aux, 18), h = __shfl(aux, 19);
        float obj = __shfl(aux, 20);
        if (lane == 0) {
            float hw = w * 0.5f, hh = h * 0.5f;
            cls_v[v] = i1;
            score_v[v] = obj * v1;
            conf_v[v] = v1;
            box_v[v] = make_float4(x - hw, y - hh, x + hw, y + hh);
        }
    }
}

// ---------------- stage2+3: per-class compact (LDS, contention-free) + sort + NMS
__global__ __launch_bounds__(256) void k_nms(const int* __restrict__ vcount,
                                             const int* __restrict__ vidx,
                                             const int* __restrict__ cls_v,
                                             const float* __restrict__ score_v,
                                             const float* __restrict__ conf_v,
                                             const float4* __restrict__ box_v,
                                             unsigned long long* __restrict__ pool_key,
                                             float* __restrict__ pool_conf,
                                             int* __restrict__ pool_cls,
                                             int* __restrict__ pool_count) {
    __shared__ unsigned long long key[CAP];   // (~score_bits)<<32 | orig_idx
    __shared__ int vslot[CAP];
    __shared__ float4 bx[CAP];
    __shared__ float cf[CAP];
    __shared__ unsigned words[CAP / 32];      // alive bitmask
    __shared__ int s_n, s_cur;
    const int c = blockIdx.x;
    const int t = threadIdx.x, lane = t & 63;
    const int total = min(*vcount, VMAX);

    for (int p = t; p < CAP; p += 256) key[p] = ~0ULL;
    if (t == 0) s_n = 0;
    __syncthreads();

    // compaction scan over all valid boxes; 4 independent chunks/iter to hide L2 latency
    for (int v0 = 0; v0 < total; v0 += 1024) {
        #pragma unroll
        for (int q = 0; q < 4; q++) {
            int v = v0 + (q << 8) + t;
            bool mm = (v < total) && (cls_v[v] == c);
            unsigned long long bal = __ballot(mm);
            if (bal) {   // wave-uniform
                int wb;
                if (lane == 0) wb = atomicAdd(&s_n, (int)__popcll(bal));  // LDS atomic
                wb = __shfl(wb, 0);
                if (mm) {
                    int pos = wb + (int)__popcll(bal & ((1ull << lane) - 1ull));
                    if (pos < CAP) {
                        unsigned sb = __float_as_uint(score_v[v]);  // score >= 0
                        key[pos] = ((unsigned long long)(~sb) << 32) | (unsigned)vidx[v];
                        vslot[pos] = v;
                    }
                }
            }
        }
    }
    __syncthreads();
    const int n = min(s_n, CAP);
    if (t < CAP / 32) {
        int lo = t << 5;
        words[t] = (n >= lo + 32) ? 0xFFFFFFFFu
                                  : (n > lo ? ((1u << (n - lo)) - 1u) : 0u);
    }

    // bitonic sort ascending: score desc, ties orig-idx asc (stable-argsort match)
    for (int k = 2; k <= CAP; k <<= 1) {
        for (int j = k >> 1; j > 0; j >>= 1) {
            for (int i = t; i < CAP; i += 256) {
                int ixj = i ^ j;
                if (ixj > i) {
                    unsigned long long a = key[i], b = key[ixj];
                    if ((a > b) == ((i & k) == 0)) {
                        key[i] = b; key[ixj] = a;
                        int sv = vslot[i]; vslot[i] = vslot[ixj]; vslot[ixj] = sv;
                    }
                }
            }
            __syncthreads();
        }
    }

    // gather payload in sorted order (global reads, L2/L3-hot)
    for (int p = t; p < n; p += 256) {
        int v = vslot[p];
        bx[p] = box_v[v];
        cf[p] = conf_v[v];
    }

    // greedy NMS: bitmask find-first + parallel IoU pass per pick
    int cur = -1;
    const int nw = (n + 31) >> 5;
    while (true) {
        __syncthreads();   // publish payload / bitmask updates
        if (t == 0) {
            int nxt = -1;
            int start = cur + 1;
            if (start < n) {
                int w = start >> 5;
                unsigned m = words[w] & (0xFFFFFFFFu << (start & 31));
                while (true) {
                    if (m) { nxt = (w << 5) + __ffs(m) - 1; break; }
                    if (++w >= nw) break;
                    m = words[w];
                }
            }
            s_cur = nxt;
        }
        __syncthreads();
        cur = s_cur;
        if (cur < 0) break;

        float4 curb = bx[cur];
        float a1 = (curb.z - curb.x + 1.0f) * (curb.w - curb.y + 1.0f);
        for (int j = cur + 1 + t; j < n; j += 256) {
            if ((words[j >> 5] >> (j & 31)) & 1u) {
                float4 b = bx[j];
                float xx1 = fmaxf(curb.x, b.x);
                float yy1 = fmaxf(curb.y, b.y);
                float xx2 = fminf(curb.z, b.z);
                float yy2 = fminf(curb.w, b.w);
                float iw = xx2 - xx1 + 1.0f;
                float ih = yy2 - yy1 + 1.0f;
                float inter = fmaxf(iw, 0.0f) * fmaxf(ih, 0.0f);
                float a2 = (b.z - b.x + 1.0f) * (b.w - b.y + 1.0f);
                float iou = inter / (a1 + a2 - inter + 1e-16f);
                if (iou > 0.4f)   // NMS_THRES
                    atomicAnd(&words[j >> 5], ~(1u << (j & 31)));
            }
        }
        if (t == 0) {
            int pp = atomicAdd(pool_count, 1);
            if (pp < POOL) {
                unsigned long long lk = key[cur];
                // repack: (~score)<<31 | orig_idx(18b)<<13 | pool_idx(13b)
                pool_key[pp] = ((lk >> 32) << 31) | ((lk & 0xFFFFFFFFull) << 13) |
                               (unsigned long long)pp;
                pool_conf[pp] = cf[cur];
                pool_cls[pp] = c;
            }
        }
    }
}

// ---------------- stage4: global top-300 by score-key, then conf re-sort, output
__global__ __launch_bounds__(1024) void k_final(const unsigned long long* __restrict__ pool_key,
                                                const float* __restrict__ pool_conf,
                                                const int* __restrict__ pool_cls,
                                                const int* __restrict__ pool_count,
                                                float* __restrict__ out) {
    __shared__ unsigned long long skey[POOL];  // 64 KB
    const int t = threadIdx.x;
    const int K = min(*pool_count, POOL);
    for (int i = t; i < POOL; i += 1024) skey[i] = (i < K) ? pool_key[i] : ~0ULL;
    __syncthreads();

    int P = 512;
    while (P < K) P <<= 1;  // runtime-sized bitonic, P >= 512 > 300
    for (int k = 2; k <= P; k <<= 1) {
        for (int j = k >> 1; j > 0; j >>= 1) {
            for (int i = t; i < P; i += 1024) {
                int ixj = i ^ j;
                if (ixj > i) {
                    unsigned long long a = skey[i], b = skey[ixj];
                    if ((a > b) == ((i & k) == 0)) { skey[i] = b; skey[ixj] = a; }
                }
            }
            __syncthreads();
        }
    }

    // Final order: conf desc, ties slot desc (= reversed stable argsort)
    const int M = min(K, 300);
    unsigned long long k2 = ~0ULL;
    unsigned cb = 0;
    int mycls = 0;
    if (t < M) {
        int pidx = (int)(skey[t] & 0x1FFFull);
        float cfv = pool_conf[pidx];
        mycls = pool_cls[pidx];
        cb = __float_as_uint(cfv);
        k2 = ((unsigned long long)(~cb) << 32) | (unsigned)(~t);
    }
    __syncthreads();
    if (t < 512) skey[t] = k2;  // t in [M,512) pads with ~0ULL
    if (t < M) {
        skey[1024 + t] = cb;
        skey[2048 + t] = (unsigned long long)(unsigned)mycls;
    }
    __syncthreads();
    for (int k = 2; k <= 512; k <<= 1) {
        for (int j = k >> 1; j > 0; j >>= 1) {
            for (int i = t; i < 512; i += 1024) {
                int ixj = i ^ j;
                if (ixj > i) {
                    unsigned long long a = skey[i], b = skey[ixj];
                    if ((a > b) == ((i & k) == 0)) { skey[i] = b; skey[ixj] = a; }
                }
            }
            __syncthreads();
        }
    }

    if (t < 300) {
        float idv = 0.0f, pv = 0.0f;
        if (t < M) {
            unsigned long long kk = skey[t];
            int slotv = (int)(~(unsigned)(kk & 0xFFFFFFFFull));
            pv = __uint_as_float((unsigned)skey[1024 + slotv]);
            idv = (float)(int)skey[2048 + slotv];
        }
        out[t] = idv;        // ids (1,300)
        out[300 + t] = pv;   // probs (300,)
    }
}

extern "C" void kernel_launch(void* const* d_in, const int* in_sizes, int n_in,
                              void* d_out, int out_size, void* d_ws, size_t ws_size,
                              hipStream_t stream) {
    const float* det = (const float*)d_in[0];
    float* out = (float*)d_out;
    char* ws = (char*)d_ws;

    // workspace layout (~4.3 MB)
    int* vcount = (int*)(ws + 0);
    int* pool_count = (int*)(ws + 4);
    int* vidx = (int*)(ws + 64);                      // VMAX*4 = 524288
    int* cls_v = (int*)(ws + 524352);                 // 524288
    float* score_v = (float*)(ws + 1048640);          // 524288
    float* conf_v = (float*)(ws + 1572928);           // 524288
    float4* box_v = (float4*)(ws + 2097216);          // VMAX*16 = 2097152 (16B aligned)
    unsigned long long* pool_key = (unsigned long long*)(ws + 4194368);  // 65536
    float* pool_conf = (float*)(ws + 4259904);        // 32768
    int* pool_cls = (int*)(ws + 4292672);             // 32768

    k_init<<<1, 64, 0, stream>>>(vcount, pool_count);
    k_scan<<<NBOX / 256, 256, 0, stream>>>(det, vcount, vidx);
    k_classify<<<8192, 256, 0, stream>>>(det, vcount, vidx, cls_v, score_v, conf_v, box_v);
    k_nms<<<NCLS, 256, 0, stream>>>(vcount, vidx, cls_v, score_v, conf_v, box_v,
                                    pool_key, pool_conf, pool_cls, pool_count);
    k_final<<<1, 1024, 0, stream>>>(pool_key, pool_conf, pool_cls, pool_count, out);
}

// Round 5
// 235.977 us; speedup vs baseline: 1.6802x; 1.2016x over previous
//
#include <hip/hip_runtime.h>

#pragma clang fp contract(off)

#define NBOX 262144
#define NCLS 80
#define ROWS 85
#define CAP 1024
#define POOL 8192
#define VMAX 131072
#define TB 128   // boxes per stage1 block

typedef unsigned long long ull;

// ---------------- init: zero the two scalar counters
__global__ __launch_bounds__(64) void k_init(int* __restrict__ vcount,
                                             int* __restrict__ pool_count) {
    if (threadIdx.x == 0) { *vcount = 0; *pool_count = 0; }
}

// ---------------- stage1: coalesced LDS staging + argmax + ballot-compacted dense output
__global__ __launch_bounds__(256) void k_stage1(const float4* __restrict__ det4,
                                                int* __restrict__ vcount,
                                                int* __restrict__ cls_v,
                                                ull* __restrict__ key_v,
                                                float* __restrict__ conf_v,
                                                float4* __restrict__ box_v) {
    __shared__ float4 s4[TB * ROWS / 4];   // 43,520 B
    __shared__ int wsum[4];
    __shared__ int wbase;
    float* s = (float*)s4;
    const int t = threadIdx.x;
    const long long base4 = (long long)blockIdx.x * (TB * ROWS / 4);

    for (int i = t; i < TB * ROWS / 4; i += 256) s4[i] = det4[base4 + i];
    __syncthreads();

    const int b = t >> 1, sub = t & 1;
    const float* p = s + b * ROWS;
    const int cbase = 5 + sub * 40;
    float mx = p[cbase];
    int am = sub * 40;
    #pragma unroll 8
    for (int j = 1; j < 40; j++) {
        float v = p[cbase + j];
        if (v > mx) { mx = v; am = sub * 40 + j; }   // strict > = first occurrence
    }
    float omx = __shfl_xor(mx, 1);
    int oam = __shfl_xor(am, 1);

    bool valid = false;
    float obj = 0, x = 0, y = 0, w = 0, h = 0;
    if (sub == 0) {
        if (omx > mx) { mx = omx; am = oam; }   // higher classes only on strict >
        obj = p[4];
        valid = (obj >= 0.8f);   // CONF_THRES
        x = p[0]; y = p[1]; w = p[2]; h = p[3];
    }
    ull bal = __ballot(valid);   // odd lanes contribute 0
    const int wid = t >> 6, lane = t & 63;
    if (lane == 0) wsum[wid] = (int)__popcll(bal);
    __syncthreads();
    if (t == 0) {
        int sacc = 0;
        #pragma unroll
        for (int q = 0; q < 4; q++) { int cq = wsum[q]; wsum[q] = sacc; sacc += cq; }
        wbase = atomicAdd(vcount, sacc);   // ONE global atomic per block
    }
    __syncthreads();
    if (valid) {
        int pos = wbase + wsum[wid] + (int)__popcll(bal & ((1ull << lane) - 1ull));
        if (pos < VMAX) {
            int gi = blockIdx.x * TB + b;
            float score = obj * mx;
            float hw = w * 0.5f, hh = h * 0.5f;
            cls_v[pos] = am;
            key_v[pos] = ((ull)(~__float_as_uint(score)) << 32) | (unsigned)gi;
            conf_v[pos] = mx;
            box_v[pos] = make_float4(x - hw, y - hh, x + hw, y + hh);
        }
    }
}

// ---------------- stage2+3: per-class compact (LDS) + sort-free register greedy NMS
__global__ __launch_bounds__(512) void k_nms(const int* __restrict__ vcount,
                                             const int* __restrict__ cls_v,
                                             const ull* __restrict__ key_v,
                                             const float* __restrict__ conf_v,
                                             const float4* __restrict__ box_v,
                                             ull* __restrict__ pool_key,
                                             float* __restrict__ pool_conf,
                                             int* __restrict__ pool_cls,
                                             int* __restrict__ pool_count) {
    __shared__ ull skey[CAP];      // 8 KB
    __shared__ float4 sbox[CAP];   // 16 KB
    __shared__ float sconf[CAP];   // 4 KB
    __shared__ ull pkey[CAP];      // pick buffer, 8 KB
    __shared__ float pconf[CAP];   // 4 KB
    __shared__ int s_n;
    const int c = blockIdx.x;
    const int t = threadIdx.x, lane = t & 63;
    const int total = min(*vcount, VMAX);

    if (t == 0) s_n = 0;
    __syncthreads();

    // compaction: 4 independent chunks/iter for L2-latency ILP
    for (int v0 = 0; v0 < total; v0 += 2048) {
        #pragma unroll
        for (int q = 0; q < 4; q++) {
            int v = v0 + (q << 9) + t;
            bool mm = (v < total) && (cls_v[v] == c);
            ull bal = __ballot(mm);
            if (bal) {   // wave-uniform
                int wb;
                if (lane == 0) wb = atomicAdd(&s_n, (int)__popcll(bal));  // LDS atomic
                wb = __shfl(wb, 0);
                if (mm) {
                    int pos = wb + (int)__popcll(bal & ((1ull << lane) - 1ull));
                    if (pos < CAP) {
                        skey[pos] = key_v[v];
                        sbox[pos] = box_v[v];
                        sconf[pos] = conf_v[v];
                    }
                }
            }
        }
    }
    __syncthreads();
    const int n = min(s_n, CAP);

    // wave 0: greedy NMS, keys register-resident, no barriers/atomics in loop
    if (t < 64) {
        ull k[16];
        #pragma unroll
        for (int j = 0; j < 16; j++) {
            int pos = lane + (j << 6);
            k[j] = (pos < n) ? skey[pos] : ~0ULL;
        }
        int np = 0;
        while (true) {
            // local argmin over 16 registers (alive = key != MAX; keys unique)
            ull lm = k[0]; int lj = 0;
            #pragma unroll
            for (int j = 1; j < 16; j++)
                if (k[j] < lm) { lm = k[j]; lj = j; }
            // wave min
            ull gm = lm;
            #pragma unroll
            for (int off = 32; off; off >>= 1) {
                ull o = __shfl_xor(gm, off);
                if (o < gm) gm = o;
            }
            if (gm == ~0ULL) break;
            // winner clears its slot; broadcast compacted position
            int wpos = 0;
            bool win = (lm == gm);
            if (win) { wpos = lane + (lj << 6); k[lj] = ~0ULL; }
            ull wb2 = __ballot(win);
            int wl = (int)__ffsll((long long)wb2) - 1;
            int cpos = __shfl(wpos, wl);

            float4 cb = sbox[cpos];   // LDS broadcast (same address, free)
            float a1 = (cb.z - cb.x + 1.0f) * (cb.w - cb.y + 1.0f);
            #pragma unroll
            for (int j = 0; j < 16; j++) {
                if (k[j] != ~0ULL) {
                    int pos = lane + (j << 6);
                    float4 bb = sbox[pos];
                    float xx1 = fmaxf(cb.x, bb.x);
                    float yy1 = fmaxf(cb.y, bb.y);
                    float xx2 = fminf(cb.z, bb.z);
                    float yy2 = fminf(cb.w, bb.w);
                    float iw = xx2 - xx1 + 1.0f;
                    float ih = yy2 - yy1 + 1.0f;
                    float inter = fmaxf(iw, 0.0f) * fmaxf(ih, 0.0f);
                    float a2 = (bb.z - bb.x + 1.0f) * (bb.w - bb.y + 1.0f);
                    float iou = inter / (a1 + a2 - inter + 1e-16f);
                    if (iou > 0.4f) k[j] = ~0ULL;   // NMS_THRES
                }
            }
            if (lane == 0) { pkey[np] = gm; pconf[np] = sconf[cpos]; }
            np++;
        }
        // single pool append per class
        int base;
        if (lane == 0) base = atomicAdd(pool_count, np);
        base = __shfl(base, 0);
        for (int j = lane; j < np; j += 64) {
            int pp = base + j;
            if (pp < POOL) {
                ull lk = pkey[j];
                // repack: (~score)<<31 | orig_idx(18b)<<13 | pool_idx(13b)
                pool_key[pp] = ((lk >> 32) << 31) | ((lk & 0xFFFFFFFFull) << 13) | (ull)pp;
                pool_conf[pp] = pconf[j];
                pool_cls[pp] = c;
            }
        }
    }
}

// ---------------- stage4: global top-300 by score-key, then conf re-sort, output
__global__ __launch_bounds__(1024) void k_final(const ull* __restrict__ pool_key,
                                                const float* __restrict__ pool_conf,
                                                const int* __restrict__ pool_cls,
                                                const int* __restrict__ pool_count,
                                                float* __restrict__ out) {
    __shared__ ull skey[POOL];  // 64 KB
    const int t = threadIdx.x;
    const int K = min(*pool_count, POOL);
    for (int i = t; i < POOL; i += 1024) skey[i] = (i < K) ? pool_key[i] : ~0ULL;
    __syncthreads();

    int P = 512;
    while (P < K) P <<= 1;
    for (int k = 2; k <= P; k <<= 1) {
        for (int j = k >> 1; j > 0; j >>= 1) {
            for (int i = t; i < P; i += 1024) {
                int ixj = i ^ j;
                if (ixj > i) {
                    ull a = skey[i], b = skey[ixj];
                    if ((a > b) == ((i & k) == 0)) { skey[i] = b; skey[ixj] = a; }
                }
            }
            __syncthreads();
        }
    }

    // Final order: conf desc, ties slot desc (= reversed stable argsort)
    const int M = min(K, 300);
    ull k2 = ~0ULL;
    unsigned cb = 0;
    int mycls = 0;
    if (t < M) {
        int pidx = (int)(skey[t] & 0x1FFFull);
        float cfv = pool_conf[pidx];
        mycls = pool_cls[pidx];
        cb = __float_as_uint(cfv);
        k2 = ((ull)(~cb) << 32) | (unsigned)(~t);
    }
    __syncthreads();
    if (t < 512) skey[t] = k2;  // t in [M,512) pads with ~0ULL
    if (t < M) {
        skey[1024 + t] = cb;
        skey[2048 + t] = (ull)(unsigned)mycls;
    }
    __syncthreads();
    for (int k = 2; k <= 512; k <<= 1) {
        for (int j = k >> 1; j > 0; j >>= 1) {
            for (int i = t; i < 512; i += 1024) {
                int ixj = i ^ j;
                if (ixj > i) {
                    ull a = skey[i], b = skey[ixj];
                    if ((a > b) == ((i & k) == 0)) { skey[i] = b; skey[ixj] = a; }
                }
            }
            __syncthreads();
        }
    }

    if (t < 300) {
        float idv = 0.0f, pv = 0.0f;
        if (t < M) {
            ull kk = skey[t];
            int slotv = (int)(~(unsigned)(kk & 0xFFFFFFFFull));
            pv = __uint_as_float((unsigned)skey[1024 + slotv]);
            idv = (float)(int)skey[2048 + slotv];
        }
        out[t] = idv;        // ids (1,300)
        out[300 + t] = pv;   // probs (300,)
    }
}

extern "C" void kernel_launch(void* const* d_in, const int* in_sizes, int n_in,
                              void* d_out, int out_size, void* d_ws, size_t ws_size,
                              hipStream_t stream) {
    const float4* det4 = (const float4*)d_in[0];
    float* out = (float*)d_out;
    char* ws = (char*)d_ws;

    // workspace layout (~4.3 MB)
    int* vcount = (int*)(ws + 0);
    int* pool_count = (int*)(ws + 4);
    int* cls_v = (int*)(ws + 64);                     // VMAX*4 = 524288
    ull* key_v = (ull*)(ws + 524352);                 // VMAX*8 = 1048576
    float* conf_v = (float*)(ws + 1572928);           // 524288
    float4* box_v = (float4*)(ws + 2097216);          // VMAX*16 = 2097152 (16B aligned)
    ull* pool_key = (ull*)(ws + 4194368);             // 65536
    float* pool_conf = (float*)(ws + 4259904);        // 32768
    int* pool_cls = (int*)(ws + 4292672);             // 32768

    k_init<<<1, 64, 0, stream>>>(vcount, pool_count);
    k_stage1<<<NBOX / TB, 256, 0, stream>>>(det4, vcount, cls_v, key_v, conf_v, box_v);
    k_nms<<<NCLS, 512, 0, stream>>>(vcount, cls_v, key_v, conf_v, box_v,
                                    pool_key, pool_conf, pool_cls, pool_count);
    k_final<<<1, 1024, 0, stream>>>(pool_key, pool_conf, pool_cls, pool_count, out);
}